// Round 7
// baseline (23.721 us; speedup 1.0000x reference)
//
#include <hip/hip_runtime.h>

// GPTQ W4A32 linear via bf16 MFMA, magic-mantissa dequant, fused x-staging.
// out(16,11008) = x(16,4096) @ W,  W[k][n] = s[g][n]*(w4[k][n] - z4[g][n]).
// bf16 bits (0x4380|w) == 256+2w exactly -> MFMA on raw nibbles gives
// P_raw = 256*X + 2*P per group (X = group-sum of bf16-rounded x):
// out += (s/2)*P_raw - s*(128+z)*X.  Mask-trick nibble order k={0,4,1,5,2,6,3,7}
// per 8; x staged to LDS with same permutation, XOR-swizzled (^(m&7)<<4).
// R5 lesson: no device-scope fences (320us). R7: x loads issued BEFORE
// qweight (vmcnt drains in order -> old prefetch order serialized staging);
// X-sum folded into staging via shfl butterfly (one barrier, no idle waves);
// qweight software-pipelined across the group loop.

#define M_DIM 16
#define K_DIM 4096
#define N_DIM 11008
#define GS 128
#define KSPLIT 8
#define KC (K_DIM / KSPLIT)      // 512 k per block chunk
#define GPC (KC / GS)            // 4 groups per chunk
#define BLOCKN 64                // 4 waves x 16 n
#define NTHREADS 256

typedef __attribute__((ext_vector_type(8))) short short8;
typedef __attribute__((ext_vector_type(4))) float f32x4;

__device__ __forceinline__ float bfl(unsigned w) {
    union { unsigned u; float f; } c; c.u = w << 16; return c.f;
}
__device__ __forceinline__ float bfh(unsigned w) {
    union { unsigned u; float f; } c; c.u = w & 0xFFFF0000u; return c.f;
}

__global__ __launch_bounds__(NTHREADS, 8) void qlin_fused(
    const float* __restrict__ x,
    const int*   __restrict__ qweight,
    const float* __restrict__ scales,
    const int*   __restrict__ qzeros,
    float*       __restrict__ outp,   // partials [KSPLIT][16][N] or out [16][N]
    int nchunks)
{
    __shared__ __align__(16) unsigned short xs[M_DIM * KC];  // 16 KiB swizzled
    __shared__ __align__(16) float Xl[GPC * 16];

    const int tid  = threadIdx.x;
    const int lane = tid & 63, wave = tid >> 6;
    const int lmod = lane & 15, lhi = lane >> 4;
    const int n    = blockIdx.x * BLOCKN + wave * 16 + lmod;
    const int swzA = (lmod & 7) << 4;
    const int zsh  = (n & 7) * 4;

    f32x4 outacc = {0.f, 0.f, 0.f, 0.f};

    for (int c = 0; c < nchunks; ++c) {
        const int ky0 = (blockIdx.y * nchunks + c) * KC;
        const int G0 = ky0 / GS, rowbase = ky0 >> 3;

        __syncthreads();   // protect xs/Xl from previous chunk readers

        // ---- phase A: x staging (loads issued FIRST), X folded in.
        // thread covers cc = lane (8 k at cc*8, all in group g = lane>>4),
        // rows m = 4i + wave, i = 0..3.  Two batches to cap VGPR pressure.
        const float* xb = x + ky0 + (size_t)lane * 8;
        float Xp[4];
#pragma unroll
        for (int h = 0; h < 2; ++h) {
            float4 v0[2], v1[2];
#pragma unroll
            for (int i = 0; i < 2; ++i) {
                const float4* xp =
                    (const float4*)(xb + (size_t)((h * 2 + i) * 4 + wave) * K_DIM);
                v0[i] = xp[0]; v1[i] = xp[1];
            }
#pragma unroll
            for (int i = 0; i < 2; ++i) {
                const int m = (h * 2 + i) * 4 + wave;
                union { short8 s; unsigned u[4]; } pk;
                asm("v_cvt_pk_bf16_f32 %0, %1, %2" : "=v"(pk.u[0]) : "v"(v0[i].x), "v"(v1[i].x));
                asm("v_cvt_pk_bf16_f32 %0, %1, %2" : "=v"(pk.u[1]) : "v"(v0[i].y), "v"(v1[i].y));
                asm("v_cvt_pk_bf16_f32 %0, %1, %2" : "=v"(pk.u[2]) : "v"(v0[i].z), "v"(v1[i].z));
                asm("v_cvt_pk_bf16_f32 %0, %1, %2" : "=v"(pk.u[3]) : "v"(v0[i].w), "v"(v1[i].w));
                const int byte = ((m * KC + lane * 8) * 2) ^ ((m & 7) << 4);
                *(short8*)((char*)xs + byte) = pk.s;
                float s = 0.f;
#pragma unroll
                for (int p = 0; p < 4; ++p) s += bfl(pk.u[p]) + bfh(pk.u[p]);
                Xp[h * 2 + i] = s;
            }
        }

        // ---- group meta for all groups + qweight for group 0 (these loads
        // are younger than the x loads, so they never block the ds_writes)
        float sg[GPC]; unsigned zg[GPC];
#pragma unroll
        for (int g = 0; g < GPC; ++g) {
            sg[g] = scales[(size_t)(G0 + g) * N_DIM + n];
            zg[g] = (unsigned)qzeros[(size_t)(G0 + g) * (N_DIM / 8) + (n >> 3)];
        }
        unsigned qwc[4], qwn[4];
#pragma unroll
        for (int t = 0; t < 4; ++t)
            qwc[t] = (unsigned)qweight[(size_t)(rowbase + t * 4 + lhi) * N_DIM + n];

        // ---- X butterfly (width-16) and LDS publish
#pragma unroll
        for (int i = 0; i < 4; ++i) {
            Xp[i] += __shfl_xor(Xp[i], 1, 16);
            Xp[i] += __shfl_xor(Xp[i], 2, 16);
            Xp[i] += __shfl_xor(Xp[i], 4, 16);
            Xp[i] += __shfl_xor(Xp[i], 8, 16);
        }
        if ((lane & 15) == 0) {
#pragma unroll
            for (int i = 0; i < 4; ++i)
                Xl[lhi * 16 + i * 4 + wave] = Xp[i];   // Xl[g][m]
        }
        __syncthreads();

        // ---- MFMA over GPC groups; qweight pipelined one group ahead
#pragma unroll
        for (int g = 0; g < GPC; ++g) {
            if (g + 1 < GPC) {
#pragma unroll
                for (int t = 0; t < 4; ++t)
                    qwn[t] = (unsigned)
                        qweight[(size_t)(rowbase + (g + 1) * 16 + t * 4 + lhi) * N_DIM + n];
            }
            f32x4 acc = {0.f, 0.f, 0.f, 0.f};
#pragma unroll
            for (int t = 0; t < 4; ++t) {
                union { short8 v; unsigned u[4]; } b;
                const unsigned q = qwc[t];
                b.u[0] = ( q        & 0x000F000Fu) | 0x43804380u;
                b.u[1] = ((q >> 4)  & 0x000F000Fu) | 0x43804380u;
                b.u[2] = ((q >> 8)  & 0x000F000Fu) | 0x43804380u;
                b.u[3] = ((q >> 12) & 0x000F000Fu) | 0x43804380u;
                const int byte =
                    ((lmod * KC + g * GS + t * 32 + lhi * 8) * 2) ^ swzA;
                const short8 a = *(const short8*)((const char*)xs + byte);
                acc = __builtin_amdgcn_mfma_f32_16x16x32_bf16(a, b.v, acc, 0, 0, 0);
            }
#pragma unroll
            for (int t = 0; t < 4; ++t) qwc[t] = qwn[t];

            const f32x4 x4 = *(const f32x4*)&Xl[g * 16 + lhi * 4];
            const float z  = (float)((zg[g] >> zsh) & 15u);
            const float s2 = 0.5f * sg[g];
            const float zc = -sg[g] * (128.0f + z);
#pragma unroll
            for (int r = 0; r < 4; ++r)
                outacc[r] = fmaf(s2, acc[r], fmaf(zc, x4[r], outacc[r]));
        }
    }

#pragma unroll
    for (int r = 0; r < 4; ++r)
        outp[(size_t)(blockIdx.y * M_DIM + lhi * 4 + r) * N_DIM + n] = outacc[r];
}

__global__ __launch_bounds__(256) void qlin_reduce(
    const float* __restrict__ part, float* __restrict__ out)
{
    const int i = blockIdx.x * 256 + threadIdx.x;   // over M*N
    if (i < M_DIM * N_DIM) {
        float s = 0.f;
#pragma unroll
        for (int c = 0; c < KSPLIT; ++c)
            s += part[(size_t)c * M_DIM * N_DIM + i];
        out[i] = s;
    }
}

extern "C" void kernel_launch(void* const* d_in, const int* in_sizes, int n_in,
                              void* d_out, int out_size, void* d_ws, size_t ws_size,
                              hipStream_t stream) {
    const float* x       = (const float*)d_in[0];
    const int*   qweight = (const int*)d_in[1];
    const float* scales  = (const float*)d_in[2];
    const int*   qzeros  = (const int*)d_in[3];
    float*       out     = (float*)d_out;

    const size_t part_bytes = (size_t)KSPLIT * M_DIM * N_DIM * sizeof(float);
    if (ws_size >= part_bytes) {
        float* part = (float*)d_ws;
        dim3 grid(N_DIM / BLOCKN, KSPLIT);          // (172, 8)
        qlin_fused<<<grid, NTHREADS, 0, stream>>>(x, qweight, scales, qzeros,
                                                  part, 1);
        qlin_reduce<<<(M_DIM * N_DIM + 255) / 256, 256, 0, stream>>>(part, out);
    } else {
        dim3 grid(N_DIM / BLOCKN, 1);
        qlin_fused<<<grid, NTHREADS, 0, stream>>>(x, qweight, scales, qzeros,
                                                  out, KSPLIT);
    }
}

// Round 8
// 18.072 us; speedup vs baseline: 1.3126x; 1.3126x over previous
//
#include <hip/hip_runtime.h>

// GPTQ W4A32 linear via bf16 MFMA, magic-mantissa dequant, fused x-staging.
// out(16,11008) = x(16,4096) @ W,  W[k][n] = s[g][n]*(w4[k][n] - z4[g][n]).
// bf16 bits (0x4380|w) == 256+2w exactly -> MFMA on raw nibbles gives
// P_raw = 256*X + 2*P per group (X = group-sum of bf16-rounded x):
// out += (s/2)*P_raw - s*(128+z)*X.  Mask-trick nibble order k={0,4,1,5,2,6,3,7}
// per 8; x staged to LDS with same permutation, XOR-swizzled (^(m&7)<<4).
//
// R4 block structure (verified 16.0us) with the epilogue replaced:
//   - KSPLIT 8->4 (KC=1024): half the blocks/barriers, 2x MLP per block
//   - split-K partials + reduce kernel REPLACED by fp32 atomicAdd into out
//     (4 adds/element; NO __threadfence -- R5's 320us disaster was the
//     device-scope fence, not atomics; atomicAdd is device-coherent)
//   - d_out zeroed via stream-ordered hipMemsetAsync (capture-legal, cf R5)
// R7 lesson: no launch_bounds min-wave cap, no manual load pipelining --
// the compiler hoists the (compile-time-addressed) qweight loads itself.

#define M_DIM 16
#define K_DIM 4096
#define N_DIM 11008
#define GS 128
#define KSPLIT 4
#define KC (K_DIM / KSPLIT)      // 1024 k per block
#define GPC (KC / GS)            // 8 groups per block
#define BLOCKN 64                // 4 waves x 16 n
#define NTHREADS 256

typedef __attribute__((ext_vector_type(8))) short short8;
typedef __attribute__((ext_vector_type(4))) float f32x4;

__device__ __forceinline__ float bfl(unsigned w) {
    union { unsigned u; float f; } c; c.u = w << 16; return c.f;
}
__device__ __forceinline__ float bfh(unsigned w) {
    union { unsigned u; float f; } c; c.u = w & 0xFFFF0000u; return c.f;
}

__global__ __launch_bounds__(NTHREADS) void qlin_fused(
    const float* __restrict__ x,
    const int*   __restrict__ qweight,
    const float* __restrict__ scales,
    const int*   __restrict__ qzeros,
    float*       __restrict__ out)    // pre-zeroed; atomic accumulate
{
    __shared__ __align__(16) unsigned short xs[M_DIM * KC];  // 32 KiB swizzled
    __shared__ __align__(16) float Xl[GPC * 16];

    const int tid  = threadIdx.x;
    const int lane = tid & 63, wave = tid >> 6;
    const int lmod = lane & 15, lhi = lane >> 4;
    const int n    = blockIdx.x * BLOCKN + wave * 16 + lmod;
    const int swzA = (lmod & 7) << 4;
    const int zsh  = (n & 7) * 4;

    const int ky0 = blockIdx.y * KC;
    const int G0 = ky0 / GS, rowbase = ky0 >> 3;

    // ---- stage x[16][KC]: f32 -> bf16 (RNE), permuted, swizzled (R4 loop)
#pragma unroll
    for (int i = 0; i < (M_DIM * KC / 8) / NTHREADS; ++i) {   // 8 iters
        const int idx = i * NTHREADS + tid;
        const int m  = idx >> 7;          // KC/8 == 128 chunks per row
        const int cc = idx & 127;
        const float4* xp =
            (const float4*)(x + (size_t)m * K_DIM + ky0 + cc * 8);
        const float4 v0 = xp[0], v1 = xp[1];
        union { short8 s; unsigned u[4]; } pk;
        asm("v_cvt_pk_bf16_f32 %0, %1, %2" : "=v"(pk.u[0]) : "v"(v0.x), "v"(v1.x));
        asm("v_cvt_pk_bf16_f32 %0, %1, %2" : "=v"(pk.u[1]) : "v"(v0.y), "v"(v1.y));
        asm("v_cvt_pk_bf16_f32 %0, %1, %2" : "=v"(pk.u[2]) : "v"(v0.z), "v"(v1.z));
        asm("v_cvt_pk_bf16_f32 %0, %1, %2" : "=v"(pk.u[3]) : "v"(v0.w), "v"(v1.w));
        const int byte = ((m * KC + cc * 8) * 2) ^ ((m & 7) << 4);
        *(short8*)((char*)xs + byte) = pk.s;
    }
    __syncthreads();

    // ---- X[g][m] = group-sum of staged bf16; wave w handles groups w, w+4
#pragma unroll
    for (int gg = wave; gg < GPC; gg += 4) {
        float xv = 0.f;
#pragma unroll
        for (int q = 0; q < 4; ++q) {
            const int byte =
                ((lmod * KC + gg * GS + lhi * 32 + q * 8) * 2) ^ swzA;
            union { short8 s; unsigned u[4]; } a;
            a.s = *(const short8*)((const char*)xs + byte);
#pragma unroll
            for (int p = 0; p < 4; ++p) xv += bfl(a.u[p]) + bfh(a.u[p]);
        }
        xv += __shfl_xor(xv, 16, 64);
        xv += __shfl_xor(xv, 32, 64);
        if (lane < 16) Xl[gg * 16 + lane] = xv;
    }
    __syncthreads();

    // ---- MFMA over 8 groups; qweight loads left to the compiler to hoist
    f32x4 outacc = {0.f, 0.f, 0.f, 0.f};
#pragma unroll
    for (int g = 0; g < GPC; ++g) {
        const float s = scales[(size_t)(G0 + g) * N_DIM + n];
        const unsigned zq =
            (unsigned)qzeros[(size_t)(G0 + g) * (N_DIM / 8) + (n >> 3)];
        f32x4 acc = {0.f, 0.f, 0.f, 0.f};
#pragma unroll
        for (int t = 0; t < 4; ++t) {
            const unsigned q = (unsigned)
                qweight[(size_t)(rowbase + g * 16 + t * 4 + lhi) * N_DIM + n];
            union { short8 v; unsigned u[4]; } b;
            b.u[0] = ( q        & 0x000F000Fu) | 0x43804380u;
            b.u[1] = ((q >> 4)  & 0x000F000Fu) | 0x43804380u;
            b.u[2] = ((q >> 8)  & 0x000F000Fu) | 0x43804380u;
            b.u[3] = ((q >> 12) & 0x000F000Fu) | 0x43804380u;
            const int byte =
                ((lmod * KC + g * GS + t * 32 + lhi * 8) * 2) ^ swzA;
            const short8 a = *(const short8*)((const char*)xs + byte);
            acc = __builtin_amdgcn_mfma_f32_16x16x32_bf16(a, b.v, acc, 0, 0, 0);
        }
        const f32x4 x4 = *(const f32x4*)&Xl[g * 16 + lhi * 4];
        const float z  = (float)((zq >> zsh) & 15u);
        const float s2 = 0.5f * s;
        const float zc = -s * (128.0f + z);
#pragma unroll
        for (int r = 0; r < 4; ++r)
            outacc[r] = fmaf(s2, acc[r], fmaf(zc, x4[r], outacc[r]));
    }

    // ---- accumulate directly into out (pre-zeroed; 4 adds per element)
#pragma unroll
    for (int r = 0; r < 4; ++r)
        atomicAdd(&out[(size_t)(lhi * 4 + r) * N_DIM + n], outacc[r]);
}

extern "C" void kernel_launch(void* const* d_in, const int* in_sizes, int n_in,
                              void* d_out, int out_size, void* d_ws, size_t ws_size,
                              hipStream_t stream) {
    const float* x       = (const float*)d_in[0];
    const int*   qweight = (const int*)d_in[1];
    const float* scales  = (const float*)d_in[2];
    const int*   qzeros  = (const int*)d_in[3];
    float*       out     = (float*)d_out;

    hipMemsetAsync(out, 0, (size_t)out_size * sizeof(float), stream);
    dim3 grid(N_DIM / BLOCKN, KSPLIT);              // (172, 4)
    qlin_fused<<<grid, NTHREADS, 0, stream>>>(x, qweight, scales, qzeros, out);
}